// Round 4
// baseline (610.691 us; speedup 1.0000x reference)
//
#include <hip/hip_runtime.h>
#include <cstdint>
#include <cstddef>

#define BB 2
#define QQ 2048
#define KK_ 2048
#define HH 16
#define DD 64
#define DVV 64
#define NEG_INF_F (-1e9f)

static constexpr size_t CTX_ELEMS = (size_t)BB * QQ * HH * DVV;  // 4,194,304

typedef _Float16 f16x8 __attribute__((ext_vector_type(8)));
typedef _Float16 f16x4 __attribute__((ext_vector_type(4)));
typedef _Float16 f16x2 __attribute__((ext_vector_type(2)));
typedef float    f32x4 __attribute__((ext_vector_type(4)));

// workspace layout (float offsets)
#define RQ_OFF    0        // [B][H][Q]  0.125*||q_row||
#define KPART_OFF 65536    // [B*H][8]   partial max ||k_row|| per chunk
#define M_OFF     65792    // [B][H][Q]  upper bound M per row

// ---------------------------------------------------------------------------
// Prep A: per (b,h,chunk): rq rows + partial kmax (over valid k only).
// ---------------------------------------------------------------------------
__global__ __launch_bounds__(256)
void prep_norms(const float* __restrict__ qs, const float* __restrict__ ks,
                const int* __restrict__ vlen, float* __restrict__ ws) {
  float* rq    = ws + RQ_OFF;
  float* kpart = ws + KPART_OFF;
  const int id = blockIdx.x;            // 0..255
  const int bh = id & 31, c = id >> 5;  // chunk 0..7
  const int h = bh & 15, b = bh >> 4;
  const int vl = vlen[b];
  const int t = threadIdx.x;
  const int grp = t >> 4, l16 = t & 15;
  const int w = t >> 6, l = t & 63;
  __shared__ float red[4];
  float km2 = 0.f;                      // max squared norm
  const int base = c * 256;
  for (int i = 0; i < 16; ++i) {
    const int r = base + i * 16 + grp;
    {
      const float4 v = *(const float4*)(qs + ((size_t)(b * QQ + r) * HH + h) * DD + l16 * 4);
      float s = v.x * v.x + v.y * v.y + v.z * v.z + v.w * v.w;
      s += __shfl_xor(s, 1); s += __shfl_xor(s, 2);
      s += __shfl_xor(s, 4); s += __shfl_xor(s, 8);
      if (l16 == 0) rq[(size_t)(b * HH + h) * QQ + r] = sqrtf(s) * 0.125f;
    }
    if (r < vl) {
      const float4 v = *(const float4*)(ks + ((size_t)(b * KK_ + r) * HH + h) * DD + l16 * 4);
      float s = v.x * v.x + v.y * v.y + v.z * v.z + v.w * v.w;
      s += __shfl_xor(s, 1); s += __shfl_xor(s, 2);
      s += __shfl_xor(s, 4); s += __shfl_xor(s, 8);
      km2 = fmaxf(km2, s);
    }
  }
  km2 = fmaxf(km2, __shfl_xor(km2, 16));
  km2 = fmaxf(km2, __shfl_xor(km2, 32));
  if (l == 0) red[w] = km2;
  __syncthreads();
  if (t == 0)
    kpart[bh * 8 + c] = sqrtf(fmaxf(fmaxf(red[0], red[1]), fmaxf(red[2], red[3])));
}

// ---------------------------------------------------------------------------
// Prep B: per (b,q): Brow = max_{k<vl} bias[q,k]; M[b,h,q] = rq*kmax + Brow.
// ---------------------------------------------------------------------------
__global__ __launch_bounds__(256)
void prep_m(const float* __restrict__ bias, const int* __restrict__ vlen,
            float* __restrict__ ws) {
  const float* rq    = ws + RQ_OFF;
  const float* kpart = ws + KPART_OFF;
  float* M = ws + M_OFF;
  const int id = blockIdx.x;            // 0..1023
  const int b = id >> 9;
  const int qb = (id & 511) * 4;
  const int t = threadIdx.x, w = t >> 6, l = t & 63;
  const int q = qb + w;
  const int vl = vlen[b];
  float m = -3e38f;
  for (int k0 = l * 4; k0 < vl; k0 += 256) {
    const float4 v = *(const float4*)(bias + (size_t)q * KK_ + k0);
    m = fmaxf(m, (k0 + 0 < vl) ? v.x : -3e38f);
    m = fmaxf(m, (k0 + 1 < vl) ? v.y : -3e38f);
    m = fmaxf(m, (k0 + 2 < vl) ? v.z : -3e38f);
    m = fmaxf(m, (k0 + 3 < vl) ? v.w : -3e38f);
  }
#pragma unroll
  for (int off = 1; off < 64; off <<= 1) m = fmaxf(m, __shfl_xor(m, off));
  if (l < 16) {
    const int h = l;
    float kmx = 0.f;
#pragma unroll
    for (int cc = 0; cc < 8; ++cc) kmx = fmaxf(kmx, kpart[(b * HH + h) * 8 + cc]);
    M[(size_t)(b * HH + h) * QQ + q] = rq[(size_t)(b * HH + h) * QQ + q] * kmx + m;
  }
}

// ---------------------------------------------------------------------------
// Main fused kernel. wg = (b,h, 64 q-rows), 256 thr (4 waves, 16 q each).
// Transposed-S MFMA: S^T = K*Q^T so each lane owns 4 CONTIGUOUS k per frag
// -> float4 bias loads, float4 nontemporal attn stores, lane-local lsum.
// Fixed per-row upper bound M (from prep) removes all per-tile reductions.
// Reg-prefetch of next K/V tile hides global latency under compute (T14).
// ---------------------------------------------------------------------------
__global__ __launch_bounds__(256, 4)
void fused_attn(const float* __restrict__ qs, const float* __restrict__ ks,
                const float* __restrict__ vs, const float* __restrict__ bias,
                const int* __restrict__ vlen, const float* __restrict__ ws,
                float* __restrict__ dout) {
  float* ctx  = dout;
  float* attn = dout + CTX_ELEMS;
  const float* Mbuf = ws + M_OFF;

  // XCD swizzle: XCD x owns q-tiles {4x..4x+3} x all 32 bh (bias L2-resident)
  const int x   = blockIdx.x;           // 0..1023
  const int xcd = x & 7;
  const int idx = x >> 3;               // 0..127, bh fastest
  const int qt  = xcd * 4 + (idx >> 5); // 0..31
  const int bh  = idx & 31;
  const int h   = bh & 15, b = bh >> 4;
  const int vl  = vlen[b];
  const int ntv = (vl + 63) >> 6;

  const int t = threadIdx.x;
  const int w = t >> 6, l = t & 63, fr = l & 15, g = l >> 4;
  const int q0 = qt * 64, qw = q0 + w * 16;
  const int myq = qw + fr;

  __shared__ _Float16 Kl[64][72];   // K tile [k][d], 144B stride (16B-aligned)
  __shared__ _Float16 Vt[64][72];   // V^T tile [dv][k]
  __shared__ _Float16 Pt[64][72];   // P tile [q][k]

  // ---- zero-fill fully-masked attn tail (nontemporal) ----
  {
    const int row = t >> 2;
    const int c0  = (t & 3) << 4;
    float* ap = attn + ((size_t)(b * HH + h) * QQ + q0 + row) * KK_ + c0;
    const f32x4 z = {0.f, 0.f, 0.f, 0.f};
    for (int k0 = ntv * 64; k0 < KK_; k0 += 64) {
      __builtin_nontemporal_store(z, (f32x4*)(ap + k0));
      __builtin_nontemporal_store(z, (f32x4*)(ap + k0 + 4));
      __builtin_nontemporal_store(z, (f32x4*)(ap + k0 + 8));
      __builtin_nontemporal_store(z, (f32x4*)(ap + k0 + 12));
    }
  }

  // ---- Q B-fragments in registers, pre-scaled by 1/8 ----
  f16x8 bq[2];
  {
    const float* qp = qs + ((size_t)(b * QQ + myq) * HH + h) * DD + g * 8;
#pragma unroll
    for (int kk = 0; kk < 2; ++kk) {
      const float4 f0 = *(const float4*)(qp + kk * 32);
      const float4 f1 = *(const float4*)(qp + kk * 32 + 4);
      f16x8 v;
      v[0] = (_Float16)(f0.x * 0.125f); v[1] = (_Float16)(f0.y * 0.125f);
      v[2] = (_Float16)(f0.z * 0.125f); v[3] = (_Float16)(f0.w * 0.125f);
      v[4] = (_Float16)(f1.x * 0.125f); v[5] = (_Float16)(f1.y * 0.125f);
      v[6] = (_Float16)(f1.z * 0.125f); v[7] = (_Float16)(f1.w * 0.125f);
      bq[kk] = v;
    }
  }

  const float Mq = Mbuf[(size_t)(b * HH + h) * QQ + myq];
  const float* biasq = bias + (size_t)myq * KK_;
  float* attnq = attn + ((size_t)(b * HH + h) * QQ + myq) * KK_;

  const int krow = t >> 2, kc0 = (t & 3) << 4;   // K staging
  const int rho = t & 31, dlt = t >> 5;          // V staging (pairs)

#define KADDR(k) (ks + ((size_t)(b * KK_ + (k)) * HH + h) * DD)
#define VADDR(k) (vs + ((size_t)(b * KK_ + (k)) * HH + h) * DVV)

#define STORE_K()                                          \
  {                                                        \
    _Pragma("unroll") for (int i = 0; i < 4; ++i) {        \
      f16x4 hv;                                            \
      hv[0] = (_Float16)kr[i].x; hv[1] = (_Float16)kr[i].y;\
      hv[2] = (_Float16)kr[i].z; hv[3] = (_Float16)kr[i].w;\
      *(f16x4*)&Kl[krow][kc0 + i * 4] = hv;                \
    }                                                      \
  }

  // ================= PASS 1: lsum with fixed M =================
  float4 kr[4];
  {
    const float* kp = KADDR(krow) + kc0;
#pragma unroll
    for (int i = 0; i < 4; ++i) kr[i] = ((const float4*)kp)[i];
  }
  STORE_K();
  __syncthreads();

  float lsum = 0.f;
  for (int it = 0; it < ntv; ++it) {
    const int k0 = it * 64;
    const bool pre = (it + 1 < ntv);
    if (pre) {
      const float* kp = KADDR(k0 + 64 + krow) + kc0;
#pragma unroll
      for (int i = 0; i < 4; ++i) kr[i] = ((const float4*)kp)[i];
    }
#pragma unroll
    for (int c = 0; c < 4; ++c) {
      f32x4 acc = {0.f, 0.f, 0.f, 0.f};
#pragma unroll
      for (int kk = 0; kk < 2; ++kk) {
        const f16x8 ka = *(const f16x8*)&Kl[c * 16 + fr][kk * 32 + g * 8];
        acc = __builtin_amdgcn_mfma_f32_16x16x32_f16(ka, bq[kk], acc, 0, 0, 0);
      }
      const int kb = k0 + c * 16 + g * 4;
      if (kb < vl) {
        const float4 bz = *(const float4*)(biasq + kb);
        const float e0 = __expf(acc[0] + bz.x - Mq);
        const float e1 = __expf(acc[1] + bz.y - Mq);
        const float e2 = __expf(acc[2] + bz.z - Mq);
        const float e3 = __expf(acc[3] + bz.w - Mq);
        lsum += (kb + 0 < vl) ? e0 : 0.f;
        lsum += (kb + 1 < vl) ? e1 : 0.f;
        lsum += (kb + 2 < vl) ? e2 : 0.f;
        lsum += (kb + 3 < vl) ? e3 : 0.f;
      }
    }
    __syncthreads();
    if (pre) {
      STORE_K();
      __syncthreads();
    }
  }
  lsum += __shfl_xor(lsum, 16);
  lsum += __shfl_xor(lsum, 32);
  const float il = 1.f / lsum;

  // ================= PASS 2: attn write + PV =================
  f32x4 accv[4];
#pragma unroll
  for (int n = 0; n < 4; ++n) accv[n] = (f32x4){0.f, 0.f, 0.f, 0.f};

  float4 vr[4];

#define LOAD_V(k0arg)                                      \
  {                                                        \
    const float* vp0 = VADDR((k0arg) + 2 * rho) + dlt * 8; \
    vr[0] = ((const float4*)vp0)[0];                       \
    vr[1] = ((const float4*)vp0)[1];                       \
    const float* vp1 = VADDR((k0arg) + 2 * rho + 1) + dlt * 8; \
    vr[2] = ((const float4*)vp1)[0];                       \
    vr[3] = ((const float4*)vp1)[1];                       \
  }

#define STORE_V()                                          \
  {                                                        \
    const float a0[8] = {vr[0].x, vr[0].y, vr[0].z, vr[0].w,\
                         vr[1].x, vr[1].y, vr[1].z, vr[1].w};\
    const float a1[8] = {vr[2].x, vr[2].y, vr[2].z, vr[2].w,\
                         vr[3].x, vr[3].y, vr[3].z, vr[3].w};\
    _Pragma("unroll") for (int i = 0; i < 8; ++i) {        \
      f16x2 pk; pk[0] = (_Float16)a0[i]; pk[1] = (_Float16)a1[i];\
      *(f16x2*)&Vt[dlt * 8 + i][2 * rho] = pk;             \
    }                                                      \
  }

  {
    const float* kp = KADDR(krow) + kc0;
#pragma unroll
    for (int i = 0; i < 4; ++i) kr[i] = ((const float4*)kp)[i];
  }
  LOAD_V(0);
  STORE_K();
  STORE_V();
  __syncthreads();

  for (int it = 0; it < ntv; ++it) {
    const int k0 = it * 64;
    const bool pre = (it + 1 < ntv);
    if (pre) {
      const float* kp = KADDR(k0 + 64 + krow) + kc0;
#pragma unroll
      for (int i = 0; i < 4; ++i) kr[i] = ((const float4*)kp)[i];
      LOAD_V(k0 + 64);
    }
#pragma unroll
    for (int c = 0; c < 4; ++c) {
      f32x4 acc = {0.f, 0.f, 0.f, 0.f};
#pragma unroll
      for (int kk = 0; kk < 2; ++kk) {
        const f16x8 ka = *(const f16x8*)&Kl[c * 16 + fr][kk * 32 + g * 8];
        acc = __builtin_amdgcn_mfma_f32_16x16x32_f16(ka, bq[kk], acc, 0, 0, 0);
      }
      const int kb = k0 + c * 16 + g * 4;
      f32x4 pv = {0.f, 0.f, 0.f, 0.f};
      if (kb < vl) {
        const float4 bz = *(const float4*)(biasq + kb);
        const float e0 = __expf(acc[0] + bz.x - Mq) * il;
        const float e1 = __expf(acc[1] + bz.y - Mq) * il;
        const float e2 = __expf(acc[2] + bz.z - Mq) * il;
        const float e3 = __expf(acc[3] + bz.w - Mq) * il;
        pv[0] = (kb + 0 < vl) ? e0 : 0.f;
        pv[1] = (kb + 1 < vl) ? e1 : 0.f;
        pv[2] = (kb + 2 < vl) ? e2 : 0.f;
        pv[3] = (kb + 3 < vl) ? e3 : 0.f;
      }
      __builtin_nontemporal_store(pv, (f32x4*)(attnq + kb));
      f16x4 ph;
      ph[0] = (_Float16)pv[0]; ph[1] = (_Float16)pv[1];
      ph[2] = (_Float16)pv[2]; ph[3] = (_Float16)pv[3];
      *(f16x4*)&Pt[w * 16 + fr][c * 16 + g * 4] = ph;
    }
    // same-wave LDS RAW on Pt: drain DS queue, then pin (rule #18)
    asm volatile("s_waitcnt lgkmcnt(0)" ::: "memory");
    __builtin_amdgcn_sched_barrier(0);
#pragma unroll
    for (int kk = 0; kk < 2; ++kk) {
      const f16x8 av = *(const f16x8*)&Pt[w * 16 + fr][kk * 32 + g * 8];
#pragma unroll
      for (int n = 0; n < 4; ++n) {
        const f16x8 bv = *(const f16x8*)&Vt[n * 16 + fr][kk * 32 + g * 8];
        accv[n] = __builtin_amdgcn_mfma_f32_16x16x32_f16(av, bv, accv[n], 0, 0, 0);
      }
    }
    __syncthreads();
    if (pre) {
      STORE_K();
      STORE_V();
      __syncthreads();
    }
  }

  // ---- ctx store: col = dv = n*16+fr, row = q = qw + g*4 + r ----
#pragma unroll
  for (int n = 0; n < 4; ++n) {
#pragma unroll
    for (int r = 0; r < 4; ++r) {
      const size_t o = ((size_t)(b * QQ + qw + g * 4 + r) * HH + h) * DVV + n * 16 + fr;
      ctx[o] = accv[n][r];
    }
  }
#undef KADDR
#undef VADDR
#undef STORE_K
#undef LOAD_V
#undef STORE_V
}

// ---------------------------------------------------------------------------
extern "C" void kernel_launch(void* const* d_in, const int* in_sizes, int n_in,
                              void* d_out, int out_size, void* d_ws, size_t ws_size,
                              hipStream_t stream) {
  (void)in_sizes; (void)n_in; (void)ws_size; (void)out_size;
  const float* qs   = (const float*)d_in[0];
  const float* ks   = (const float*)d_in[1];
  const float* vs   = (const float*)d_in[2];
  const float* bias = (const float*)d_in[3];
  const int*   vlen = (const int*)d_in[4];
  float* out = (float*)d_out;
  float* ws  = (float*)d_ws;

  prep_norms<<<dim3(256), dim3(256), 0, stream>>>(qs, ks, vlen, ws);
  prep_m<<<dim3(1024), dim3(256), 0, stream>>>(bias, vlen, ws);
  fused_attn<<<dim3(1024), dim3(256), 0, stream>>>(qs, ks, vs, bias, vlen, ws, out);
}

// Round 5
// 288.753 us; speedup vs baseline: 2.1149x; 2.1149x over previous
//
#include <hip/hip_runtime.h>
#include <cstdint>
#include <cstddef>

#define BB 2
#define QQ 2048
#define KK_ 2048
#define HH 16
#define DD 64
#define DVV 64
#define NEG_INF_F (-1e9f)

static constexpr size_t CTX_ELEMS = (size_t)BB * QQ * HH * DVV;  // 4,194,304

typedef _Float16 f16x8 __attribute__((ext_vector_type(8)));
typedef _Float16 f16x4 __attribute__((ext_vector_type(4)));
typedef _Float16 f16x2 __attribute__((ext_vector_type(2)));
typedef float    f32x4 __attribute__((ext_vector_type(4)));

// workspace layout (float offsets)
#define RQ_OFF    0        // [B][H][Q]  0.125*||q_row||
#define KPART_OFF 65536    // [B*H][8]   partial max ||k_row|| per chunk
#define M_OFF     65792    // [B][H][Q]  upper bound M per row

// ---------------------------------------------------------------------------
// Prep A: per (b,h,chunk): rq rows + partial kmax (over valid k only).
// ---------------------------------------------------------------------------
__global__ __launch_bounds__(256)
void prep_norms(const float* __restrict__ qs, const float* __restrict__ ks,
                const int* __restrict__ vlen, float* __restrict__ ws) {
  float* rq    = ws + RQ_OFF;
  float* kpart = ws + KPART_OFF;
  const int id = blockIdx.x;            // 0..255
  const int bh = id & 31, c = id >> 5;  // chunk 0..7
  const int h = bh & 15, b = bh >> 4;
  const int vl = vlen[b];
  const int t = threadIdx.x;
  const int grp = t >> 4, l16 = t & 15;
  const int w = t >> 6, l = t & 63;
  __shared__ float red[4];
  float km2 = 0.f;                      // max squared norm
  const int base = c * 256;
  for (int i = 0; i < 16; ++i) {
    const int r = base + i * 16 + grp;
    {
      const float4 v = *(const float4*)(qs + ((size_t)(b * QQ + r) * HH + h) * DD + l16 * 4);
      float s = v.x * v.x + v.y * v.y + v.z * v.z + v.w * v.w;
      s += __shfl_xor(s, 1); s += __shfl_xor(s, 2);
      s += __shfl_xor(s, 4); s += __shfl_xor(s, 8);
      if (l16 == 0) rq[(size_t)(b * HH + h) * QQ + r] = sqrtf(s) * 0.125f;
    }
    if (r < vl) {
      const float4 v = *(const float4*)(ks + ((size_t)(b * KK_ + r) * HH + h) * DD + l16 * 4);
      float s = v.x * v.x + v.y * v.y + v.z * v.z + v.w * v.w;
      s += __shfl_xor(s, 1); s += __shfl_xor(s, 2);
      s += __shfl_xor(s, 4); s += __shfl_xor(s, 8);
      km2 = fmaxf(km2, s);
    }
  }
  km2 = fmaxf(km2, __shfl_xor(km2, 16));
  km2 = fmaxf(km2, __shfl_xor(km2, 32));
  if (l == 0) red[w] = km2;
  __syncthreads();
  if (t == 0)
    kpart[bh * 8 + c] = sqrtf(fmaxf(fmaxf(red[0], red[1]), fmaxf(red[2], red[3])));
}

// ---------------------------------------------------------------------------
// Prep B: per (b,q): Brow = max_{k<vl} bias[q,k]; M[b,h,q] = rq*kmax + Brow.
// ---------------------------------------------------------------------------
__global__ __launch_bounds__(256)
void prep_m(const float* __restrict__ bias, const int* __restrict__ vlen,
            float* __restrict__ ws) {
  const float* rq    = ws + RQ_OFF;
  const float* kpart = ws + KPART_OFF;
  float* M = ws + M_OFF;
  const int id = blockIdx.x;            // 0..1023
  const int b = id >> 9;
  const int qb = (id & 511) * 4;
  const int t = threadIdx.x, w = t >> 6, l = t & 63;
  const int q = qb + w;
  const int vl = vlen[b];
  float m = -3e38f;
  for (int k0 = l * 4; k0 < vl; k0 += 256) {
    const float4 v = *(const float4*)(bias + (size_t)q * KK_ + k0);
    m = fmaxf(m, (k0 + 0 < vl) ? v.x : -3e38f);
    m = fmaxf(m, (k0 + 1 < vl) ? v.y : -3e38f);
    m = fmaxf(m, (k0 + 2 < vl) ? v.z : -3e38f);
    m = fmaxf(m, (k0 + 3 < vl) ? v.w : -3e38f);
  }
#pragma unroll
  for (int off = 1; off < 64; off <<= 1) m = fmaxf(m, __shfl_xor(m, off));
  if (l < 16) {
    const int h = l;
    float kmx = 0.f;
#pragma unroll
    for (int cc = 0; cc < 8; ++cc) kmx = fmaxf(kmx, kpart[(b * HH + h) * 8 + cc]);
    M[(size_t)(b * HH + h) * QQ + q] = rq[(size_t)(b * HH + h) * QQ + q] * kmx + m;
  }
}

// ---------------------------------------------------------------------------
// Main fused kernel. wg = (b,h, 64 q-rows), 256 thr (4 waves, 16 q each).
// Transposed-S MFMA: S^T = K*Q^T so each lane owns 4 CONTIGUOUS k per frag
// -> float4 bias loads, float4 attn stores (regular: L2 merges lines),
// lane-local lsum. Fixed per-row upper bound M removes per-tile reductions.
// Reg-prefetch of next K/V tile + hoisted unguarded bias loads hide latency.
// ---------------------------------------------------------------------------
__global__ __launch_bounds__(256, 4)
void fused_attn(const float* __restrict__ qs, const float* __restrict__ ks,
                const float* __restrict__ vs, const float* __restrict__ bias,
                const int* __restrict__ vlen, const float* __restrict__ ws,
                float* __restrict__ dout) {
  float* ctx  = dout;
  float* attn = dout + CTX_ELEMS;
  const float* Mbuf = ws + M_OFF;

  // XCD swizzle: XCD x owns q-tiles {4x..4x+3} x all 32 bh (bias L2-resident)
  const int x   = blockIdx.x;           // 0..1023
  const int xcd = x & 7;
  const int idx = x >> 3;               // 0..127, bh fastest
  const int qt  = xcd * 4 + (idx >> 5); // 0..31
  const int bh  = idx & 31;
  const int h   = bh & 15, b = bh >> 4;
  const int vl  = vlen[b];
  const int ntv = (vl + 63) >> 6;

  const int t = threadIdx.x;
  const int w = t >> 6, l = t & 63, fr = l & 15, g = l >> 4;
  const int q0 = qt * 64, qw = q0 + w * 16;
  const int myq = qw + fr;

  __shared__ _Float16 Kl[64][72];   // K tile [k][d], 144B stride (16B-aligned)
  __shared__ _Float16 Vt[64][72];   // V^T tile [dv][k]
  __shared__ _Float16 Pt[64][72];   // P tile [q][k]

  // ---- zero-fill fully-masked attn tail ----
  {
    const int row = t >> 2;
    const int c0  = (t & 3) << 4;
    float* ap = attn + ((size_t)(b * HH + h) * QQ + q0 + row) * KK_ + c0;
    const f32x4 z = {0.f, 0.f, 0.f, 0.f};
    for (int k0 = ntv * 64; k0 < KK_; k0 += 64) {
      *(f32x4*)(ap + k0)      = z;
      *(f32x4*)(ap + k0 + 4)  = z;
      *(f32x4*)(ap + k0 + 8)  = z;
      *(f32x4*)(ap + k0 + 12) = z;
    }
  }

  // ---- Q B-fragments in registers, pre-scaled by 1/8 ----
  f16x8 bq[2];
  {
    const float* qp = qs + ((size_t)(b * QQ + myq) * HH + h) * DD + g * 8;
#pragma unroll
    for (int kk = 0; kk < 2; ++kk) {
      const float4 f0 = *(const float4*)(qp + kk * 32);
      const float4 f1 = *(const float4*)(qp + kk * 32 + 4);
      f16x8 v;
      v[0] = (_Float16)(f0.x * 0.125f); v[1] = (_Float16)(f0.y * 0.125f);
      v[2] = (_Float16)(f0.z * 0.125f); v[3] = (_Float16)(f0.w * 0.125f);
      v[4] = (_Float16)(f1.x * 0.125f); v[5] = (_Float16)(f1.y * 0.125f);
      v[6] = (_Float16)(f1.z * 0.125f); v[7] = (_Float16)(f1.w * 0.125f);
      bq[kk] = v;
    }
  }

  const float Mq = Mbuf[(size_t)(b * HH + h) * QQ + myq];
  const float* biasq = bias + (size_t)myq * KK_;
  float* attnq = attn + ((size_t)(b * HH + h) * QQ + myq) * KK_;

  const int krow = t >> 2, kc0 = (t & 3) << 4;   // K staging
  const int rho = t & 31, dlt = t >> 5;          // V staging (pairs)

#define KADDR(k) (ks + ((size_t)(b * KK_ + (k)) * HH + h) * DD)
#define VADDR(k) (vs + ((size_t)(b * KK_ + (k)) * HH + h) * DVV)

#define STORE_K()                                          \
  {                                                        \
    _Pragma("unroll") for (int i = 0; i < 4; ++i) {        \
      f16x4 hv;                                            \
      hv[0] = (_Float16)kr[i].x; hv[1] = (_Float16)kr[i].y;\
      hv[2] = (_Float16)kr[i].z; hv[3] = (_Float16)kr[i].w;\
      *(f16x4*)&Kl[krow][kc0 + i * 4] = hv;                \
    }                                                      \
  }

  // ================= PASS 1: lsum with fixed M =================
  float4 kr[4];
  {
    const float* kp = KADDR(krow) + kc0;
#pragma unroll
    for (int i = 0; i < 4; ++i) kr[i] = ((const float4*)kp)[i];
  }
  STORE_K();
  __syncthreads();

  float lsum = 0.f;
  for (int it = 0; it < ntv; ++it) {
    const int k0 = it * 64;
    const bool pre = (it + 1 < ntv);
    // hoisted unconditional bias loads for the whole tile (always in-bounds)
    float4 bz[4];
#pragma unroll
    for (int c = 0; c < 4; ++c)
      bz[c] = *(const float4*)(biasq + k0 + c * 16 + g * 4);
    if (pre) {
      const float* kp = KADDR(k0 + 64 + krow) + kc0;
#pragma unroll
      for (int i = 0; i < 4; ++i) kr[i] = ((const float4*)kp)[i];
    }
#pragma unroll
    for (int c = 0; c < 4; ++c) {
      f32x4 acc = {0.f, 0.f, 0.f, 0.f};
#pragma unroll
      for (int kk = 0; kk < 2; ++kk) {
        const f16x8 ka = *(const f16x8*)&Kl[c * 16 + fr][kk * 32 + g * 8];
        acc = __builtin_amdgcn_mfma_f32_16x16x32_f16(ka, bq[kk], acc, 0, 0, 0);
      }
      const int kb = k0 + c * 16 + g * 4;
      const float e0 = __expf(acc[0] + bz[c].x - Mq);
      const float e1 = __expf(acc[1] + bz[c].y - Mq);
      const float e2 = __expf(acc[2] + bz[c].z - Mq);
      const float e3 = __expf(acc[3] + bz[c].w - Mq);
      lsum += (kb + 0 < vl) ? e0 : 0.f;
      lsum += (kb + 1 < vl) ? e1 : 0.f;
      lsum += (kb + 2 < vl) ? e2 : 0.f;
      lsum += (kb + 3 < vl) ? e3 : 0.f;
    }
    __syncthreads();
    if (pre) {
      STORE_K();
      __syncthreads();
    }
  }
  lsum += __shfl_xor(lsum, 16);
  lsum += __shfl_xor(lsum, 32);
  const float il = 1.f / lsum;

  // ================= PASS 2: attn write + PV =================
  f32x4 accv[4];
#pragma unroll
  for (int n = 0; n < 4; ++n) accv[n] = (f32x4){0.f, 0.f, 0.f, 0.f};

  float4 vr[4];

#define LOAD_V(k0arg)                                      \
  {                                                        \
    const float* vp0 = VADDR((k0arg) + 2 * rho) + dlt * 8; \
    vr[0] = ((const float4*)vp0)[0];                       \
    vr[1] = ((const float4*)vp0)[1];                       \
    const float* vp1 = VADDR((k0arg) + 2 * rho + 1) + dlt * 8; \
    vr[2] = ((const float4*)vp1)[0];                       \
    vr[3] = ((const float4*)vp1)[1];                       \
  }

#define STORE_V()                                          \
  {                                                        \
    const float a0[8] = {vr[0].x, vr[0].y, vr[0].z, vr[0].w,\
                         vr[1].x, vr[1].y, vr[1].z, vr[1].w};\
    const float a1[8] = {vr[2].x, vr[2].y, vr[2].z, vr[2].w,\
                         vr[3].x, vr[3].y, vr[3].z, vr[3].w};\
    _Pragma("unroll") for (int i = 0; i < 8; ++i) {        \
      f16x2 pk; pk[0] = (_Float16)a0[i]; pk[1] = (_Float16)a1[i];\
      *(f16x2*)&Vt[dlt * 8 + i][2 * rho] = pk;             \
    }                                                      \
  }

  {
    const float* kp = KADDR(krow) + kc0;
#pragma unroll
    for (int i = 0; i < 4; ++i) kr[i] = ((const float4*)kp)[i];
  }
  LOAD_V(0);
  STORE_K();
  STORE_V();
  __syncthreads();

  for (int it = 0; it < ntv; ++it) {
    const int k0 = it * 64;
    const bool pre = (it + 1 < ntv);
    // hoisted unconditional bias loads for the whole tile
    float4 bz[4];
#pragma unroll
    for (int c = 0; c < 4; ++c)
      bz[c] = *(const float4*)(biasq + k0 + c * 16 + g * 4);
    if (pre) {
      const float* kp = KADDR(k0 + 64 + krow) + kc0;
#pragma unroll
      for (int i = 0; i < 4; ++i) kr[i] = ((const float4*)kp)[i];
      LOAD_V(k0 + 64);
    }
#pragma unroll
    for (int c = 0; c < 4; ++c) {
      f32x4 acc = {0.f, 0.f, 0.f, 0.f};
#pragma unroll
      for (int kk = 0; kk < 2; ++kk) {
        const f16x8 ka = *(const f16x8*)&Kl[c * 16 + fr][kk * 32 + g * 8];
        acc = __builtin_amdgcn_mfma_f32_16x16x32_f16(ka, bq[kk], acc, 0, 0, 0);
      }
      const int kb = k0 + c * 16 + g * 4;
      const float e0 = __expf(acc[0] + bz[c].x - Mq) * il;
      const float e1 = __expf(acc[1] + bz[c].y - Mq) * il;
      const float e2 = __expf(acc[2] + bz[c].z - Mq) * il;
      const float e3 = __expf(acc[3] + bz[c].w - Mq) * il;
      f32x4 pv;
      pv[0] = (kb + 0 < vl) ? e0 : 0.f;
      pv[1] = (kb + 1 < vl) ? e1 : 0.f;
      pv[2] = (kb + 2 < vl) ? e2 : 0.f;
      pv[3] = (kb + 3 < vl) ? e3 : 0.f;
      *(f32x4*)(attnq + kb) = pv;   // regular store: L2 merges into full lines
      f16x4 ph;
      ph[0] = (_Float16)pv[0]; ph[1] = (_Float16)pv[1];
      ph[2] = (_Float16)pv[2]; ph[3] = (_Float16)pv[3];
      *(f16x4*)&Pt[w * 16 + fr][c * 16 + g * 4] = ph;
    }
    // same-wave LDS RAW on Pt: drain DS queue, then pin (rule #18)
    asm volatile("s_waitcnt lgkmcnt(0)" ::: "memory");
    __builtin_amdgcn_sched_barrier(0);
#pragma unroll
    for (int kk = 0; kk < 2; ++kk) {
      const f16x8 av = *(const f16x8*)&Pt[w * 16 + fr][kk * 32 + g * 8];
#pragma unroll
      for (int n = 0; n < 4; ++n) {
        const f16x8 bv = *(const f16x8*)&Vt[n * 16 + fr][kk * 32 + g * 8];
        accv[n] = __builtin_amdgcn_mfma_f32_16x16x32_f16(av, bv, accv[n], 0, 0, 0);
      }
    }
    __syncthreads();
    if (pre) {
      STORE_K();
      STORE_V();
      __syncthreads();
    }
  }

  // ---- ctx store: col = dv = n*16+fr, row = q = qw + g*4 + r ----
#pragma unroll
  for (int n = 0; n < 4; ++n) {
#pragma unroll
    for (int r = 0; r < 4; ++r) {
      const size_t o = ((size_t)(b * QQ + qw + g * 4 + r) * HH + h) * DVV + n * 16 + fr;
      ctx[o] = accv[n][r];
    }
  }
#undef KADDR
#undef VADDR
#undef STORE_K
#undef LOAD_V
#undef STORE_V
}

// ---------------------------------------------------------------------------
extern "C" void kernel_launch(void* const* d_in, const int* in_sizes, int n_in,
                              void* d_out, int out_size, void* d_ws, size_t ws_size,
                              hipStream_t stream) {
  (void)in_sizes; (void)n_in; (void)ws_size; (void)out_size;
  const float* qs   = (const float*)d_in[0];
  const float* ks   = (const float*)d_in[1];
  const float* vs   = (const float*)d_in[2];
  const float* bias = (const float*)d_in[3];
  const int*   vlen = (const int*)d_in[4];
  float* out = (float*)d_out;
  float* ws  = (float*)d_ws;

  prep_norms<<<dim3(256), dim3(256), 0, stream>>>(qs, ks, vlen, ws);
  prep_m<<<dim3(1024), dim3(256), 0, stream>>>(bias, vlen, ws);
  fused_attn<<<dim3(1024), dim3(256), 0, stream>>>(qs, ks, vs, bias, vlen, ws, out);
}